// Round 9
// baseline (363.763 us; speedup 1.0000x reference)
//
#include <hip/hip_runtime.h>
#include <hip/hip_bf16.h>
#include <math.h>

#define NTHREADS 256
#define T_STEPS 8
#define F_INC 32
#define H_DIM 128
#define O_DIM 64

typedef unsigned short u16;
typedef __attribute__((ext_vector_type(8))) short short8_t;
typedef __attribute__((ext_vector_type(4))) float float4_t;
typedef __attribute__((ext_vector_type(2))) float float2_t;

__device__ __forceinline__ float bf2f(u16 u) {
    return __uint_as_float(((unsigned)u) << 16);
}
__device__ __forceinline__ u16 f2bf(float f) {
    __hip_bfloat16 h = __float2bfloat16(f);   // RNE
    union { __hip_bfloat16 h; u16 s; } cv; cv.h = h; return cv.s;
}
// one dword (2 bf16) -> float2 {lo, hi}
__device__ __forceinline__ float2_t bfpair(unsigned u) {
    union { unsigned w[2]; float2_t f; } c;
    c.w[0] = u << 16;
    c.w[1] = u & 0xffff0000u;
    return c.f;
}
__device__ __forceinline__ void bf8_unpack(uint4 u, float* f) {
    f[0] = __uint_as_float(u.x << 16); f[1] = __uint_as_float(u.x & 0xffff0000u);
    f[2] = __uint_as_float(u.y << 16); f[3] = __uint_as_float(u.y & 0xffff0000u);
    f[4] = __uint_as_float(u.z << 16); f[5] = __uint_as_float(u.z & 0xffff0000u);
    f[6] = __uint_as_float(u.w << 16); f[7] = __uint_as_float(u.w & 0xffff0000u);
}
// fast sigmoid/tanh via v_exp_f32 (~1ulp, << bf16 noise)
__device__ __forceinline__ float fsig(float x) {
    float xc = fminf(fmaxf(x, -30.f), 30.f);
    float e = __builtin_amdgcn_exp2f(xc * -1.4426950408889634f);
    return __builtin_amdgcn_rcpf(1.0f + e);
}
__device__ __forceinline__ float ftanh(float x) {
    float xc = fminf(fmaxf(x, -15.f), 15.f);
    float e = __builtin_amdgcn_exp2f(xc * -2.8853900817779268f);
    float r = __builtin_amdgcn_rcpf(1.0f + e);
    return fmaf(-2.0f * e, r, 1.0f);
}

// ============================ CSR build + weight prep ============================
// count (blocks [0,gE)) and weight prep (blocks [gE, gE+592)) merged: independent work.
__global__ void count_wprep_kernel(const int* __restrict__ ei, int* __restrict__ cnt,
                                   int E, int gE,
                                   const float* g0, const float* g1, const float* g2,
                                   const float* i0, const float* i1, const float* i2,
                                   const float* h0, const float* h1, const float* h2,
                                   u16* o_g0, u16* o_g1, u16* o_g2,
                                   u16* o_i0, u16* o_i1, u16* o_i2,
                                   u16* o_h0, u16* o_h1, u16* o_h2) {
    if ((int)blockIdx.x < gE) {
        int e = blockIdx.x * NTHREADS + threadIdx.x;
        if (e < E) atomicAdd(&cnt[ei[E + e]], 1);   // dst row of edge_index
        return;
    }
    const int i = (blockIdx.x - gE) * NTHREADS + threadIdx.x;
    if (i < 4096)        { o_g0[i] = f2bf(g0[(i & 31) * 128 + (i >> 5)]); }
    else if (i < 20480)  { int j = i - 4096;   o_g1[j] = f2bf(g1[(j & 127) * 128 + (j >> 7)]); }
    else if (i < 36864)  { int j = i - 20480;  o_g2[j] = f2bf(g2[(j & 127) * 128 + (j >> 7)]); }
    else if (i < 69632)  { int j = i - 36864;  o_i0[j] = f2bf(i0[j]); }
    else if (i < 86016)  { int j = i - 69632;  o_i1[j] = f2bf(i1[j]); }
    else if (i < 102400) { int j = i - 86016;  o_i2[j] = f2bf(i2[j]); }
    else if (i < 118784) { int j = i - 102400; o_h0[j] = f2bf(h0[j]); }
    else if (i < 135168) { int j = i - 118784; o_h1[j] = f2bf(h1[j]); }
    else if (i < 151552) { int j = i - 135168; o_h2[j] = f2bf(h2[j]); }
}

__global__ void scan_part1(const int* __restrict__ cnt, int* __restrict__ bsum, int n) {
    __shared__ int sd[NTHREADS];
    const int i = blockIdx.x * NTHREADS + threadIdx.x;
    sd[threadIdx.x] = (i < n) ? cnt[i] : 0;
    __syncthreads();
    for (int off = 128; off > 0; off >>= 1) {
        if (threadIdx.x < off) sd[threadIdx.x] += sd[threadIdx.x + off];
        __syncthreads();
    }
    if (threadIdx.x == 0) bsum[blockIdx.x] = sd[0];
}

// inlined block-offset (wave shuffle over bsum) + scan + dis/selfw
__global__ void scan_part3(const int* __restrict__ cnt, const int* __restrict__ bsum,
                           int* __restrict__ rowptr, int* __restrict__ wp,
                           float* __restrict__ dis, float* __restrict__ selfw, int n) {
    __shared__ int sd[NTHREADS];
    __shared__ int sbase;
    const int tid = threadIdx.x;
    if (tid < 64) {
        int v0 = (tid < blockIdx.x) ? bsum[tid] : 0;   // nb <= 64
        #pragma unroll
        for (int off = 1; off < 64; off <<= 1) v0 += __shfl_xor(v0, off);
        if (tid == 0) sbase = v0;
    }
    const int i = blockIdx.x * NTHREADS + tid;
    const int v = (i < n) ? cnt[i] : 0;
    sd[tid] = v;
    __syncthreads();
    for (int off = 1; off < NTHREADS; off <<= 1) {
        const int tv = (tid >= off) ? sd[tid - off] : 0;
        __syncthreads();
        sd[tid] += tv;
        __syncthreads();
    }
    const int excl = sbase + sd[tid] - v;
    if (i < n) {
        rowptr[i] = excl; wp[i] = excl;
        if (i == n - 1) rowptr[n] = excl + v;
        const float d = 1.0f + (float)v;
        dis[i] = rsqrtf(d);
        selfw[i] = 1.0f / d;
    }
}

// packed edge metadata: epk[p] = (src, coef) -> one 8B load per edge
__global__ void fill_kernel(const int* __restrict__ ei, const float* __restrict__ dis,
                            int* __restrict__ wp, int2* __restrict__ epk, int E) {
    int e = blockIdx.x * NTHREADS + threadIdx.x;
    if (e < E) {
        int s = ei[e], d = ei[E + e];
        int p = atomicAdd(&wp[d], 1);
        epk[p] = make_int2(s, __float_as_int(dis[s] * dis[d]));
    }
}

// ============================ fused GCN layer 0: agg(x fp32) + W0 GEMM + BN ============================
// t-PAIRED: block = 16 nodes x 2 t-slices (edge metadata, staging, addresses shared).
__global__ __launch_bounds__(NTHREADS)
void gcn32_kernel(const float* __restrict__ x, const int* __restrict__ rowptr,
                  const int2* __restrict__ epk,
                  const float* __restrict__ selfw, const u16* __restrict__ Wt,
                  const float* __restrict__ bias,
                  const float* __restrict__ bng, const float* __restrict__ bnb,
                  const float* __restrict__ bnm, const float* __restrict__ bnv,
                  u16* __restrict__ out, int N) {
    constexpr int ASTR = 40;
    constexpr int ECAP = 1024;
    __shared__ __align__(16) u16 aT[2][16][ASTR];
    __shared__ int2 sM[ECAP];
    const int t0 = blockIdx.x * 2;
    const int n0 = blockIdx.y * 16;
    const int tid = threadIdx.x;
    const int wid = tid >> 6, lane = tid & 63;
    const int quad = lane >> 4, l16 = lane & 15;
    const float* xb0 = x + (long)t0 * N * 32;
    const float* xb1 = xb0 + (long)N * 32;

    const int eb0 = rowptr[n0];
    const int ecnt = min(rowptr[n0 + 16] - eb0, ECAP);
    for (int p = tid; p < ecnt; p += NTHREADS) sM[p] = epk[eb0 + p];
    __syncthreads();

    // ---- phase A: aggregate 4 nodes per wave (8 splits x 8 lanes x 4ch x 2t) ----
    const int split = lane >> 3;                  // 0..7
    const int c4 = (lane & 7) * 4;
    for (int i = 0; i < 4; ++i) {
        const int n = n0 + wid * 4 + i;
        const int l0 = rowptr[n] - eb0;
        const int l1 = rowptr[n + 1] - eb0;
        const int eL = min(l1, ecnt);
        const int start = l0 + split;
        float2_t a0[2] = {(float2_t){0.f, 0.f}, (float2_t){0.f, 0.f}};
        float2_t a1[2] = {(float2_t){0.f, 0.f}, (float2_t){0.f, 0.f}};
        #pragma unroll 2
        for (int e = start; e < eL; e += 8) {
            const int2 m = sM[e];
            const float w = __int_as_float(m.y);
            const float2_t w2 = {w, w};
            const long o = (long)m.x * 32 + c4;
            const float4 v0 = *(const float4*)(xb0 + o);
            const float4 v1 = *(const float4*)(xb1 + o);
            a0[0] = __builtin_elementwise_fma((float2_t){v0.x, v0.y}, w2, a0[0]);
            a0[1] = __builtin_elementwise_fma((float2_t){v0.z, v0.w}, w2, a0[1]);
            a1[0] = __builtin_elementwise_fma((float2_t){v1.x, v1.y}, w2, a1[0]);
            a1[1] = __builtin_elementwise_fma((float2_t){v1.z, v1.w}, w2, a1[1]);
        }
        // overflow tail (statistically never taken)
        const int kL = (eL > start) ? (eL - start + 7) >> 3 : 0;
        for (int e = start + kL * 8; e < l1; e += 8) {
            const int2 m = epk[eb0 + e];
            const float w = __int_as_float(m.y);
            const float2_t w2 = {w, w};
            const long o = (long)m.x * 32 + c4;
            const float4 v0 = *(const float4*)(xb0 + o);
            const float4 v1 = *(const float4*)(xb1 + o);
            a0[0] = __builtin_elementwise_fma((float2_t){v0.x, v0.y}, w2, a0[0]);
            a0[1] = __builtin_elementwise_fma((float2_t){v0.z, v0.w}, w2, a0[1]);
            a1[0] = __builtin_elementwise_fma((float2_t){v1.x, v1.y}, w2, a1[0]);
            a1[1] = __builtin_elementwise_fma((float2_t){v1.z, v1.w}, w2, a1[1]);
        }
        float r[8] = {a0[0][0], a0[0][1], a0[1][0], a0[1][1],
                      a1[0][0], a1[0][1], a1[1][0], a1[1][1]};
        #pragma unroll
        for (int j = 0; j < 8; ++j) {
            r[j] += __shfl_xor(r[j], 8);
            r[j] += __shfl_xor(r[j], 16);
            r[j] += __shfl_xor(r[j], 32);
        }
        if (split == 0) {
            const float sw = selfw[n];
            const float4 s0 = *(const float4*)(xb0 + (long)n * 32 + c4);
            const float4 s1 = *(const float4*)(xb1 + (long)n * 32 + c4);
            ushort4 o0, o1;
            o0.x = f2bf(fmaf(sw, s0.x, r[0])); o0.y = f2bf(fmaf(sw, s0.y, r[1]));
            o0.z = f2bf(fmaf(sw, s0.z, r[2])); o0.w = f2bf(fmaf(sw, s0.w, r[3]));
            o1.x = f2bf(fmaf(sw, s1.x, r[4])); o1.y = f2bf(fmaf(sw, s1.y, r[5]));
            o1.z = f2bf(fmaf(sw, s1.z, r[6])); o1.w = f2bf(fmaf(sw, s1.w, r[7]));
            *(ushort4*)(&aT[0][wid * 4 + i][c4]) = o0;
            *(ushort4*)(&aT[1][wid * 4 + i][c4]) = o1;
        }
    }
    __syncthreads();

    // ---- phase B: two 16x128 GEMMs vs W0t; wave owns 32 cols ----
    const short8_t fA0 = *(const short8_t*)(&aT[0][l16][quad * 8]);
    const short8_t fA1 = *(const short8_t*)(&aT[1][l16][quad * 8]);
    float4_t acc[2][2];
    short8_t fB[2];
    #pragma unroll
    for (int ct = 0; ct < 2; ++ct) {
        const int col = wid * 32 + ct * 16 + l16;
        fB[ct] = *(const short8_t*)(Wt + (long)col * 32 + quad * 8);
        acc[0][ct] = (float4_t){0.f, 0.f, 0.f, 0.f};
        acc[1][ct] = (float4_t){0.f, 0.f, 0.f, 0.f};
    }
    #pragma unroll
    for (int ct = 0; ct < 2; ++ct) {
        acc[0][ct] = __builtin_amdgcn_mfma_f32_16x16x32_bf16(fA0, fB[ct], acc[0][ct], 0, 0, 0);
        acc[1][ct] = __builtin_amdgcn_mfma_f32_16x16x32_bf16(fA1, fB[ct], acc[1][ct], 0, 0, 0);
    }

    #pragma unroll
    for (int ct = 0; ct < 2; ++ct) {
        const int c = wid * 32 + ct * 16 + l16;
        const float s = bng[c] * rsqrtf(bnv[c] + 1e-5f);
        const float a1 = bnb[c] - bnm[c] * s;
        const float a0 = bias[c];
        #pragma unroll
        for (int tt = 0; tt < 2; ++tt) {
            #pragma unroll
            for (int r = 0; r < 4; ++r) {
                const int node = quad * 4 + r;
                float v = fmaf(fmaxf(acc[tt][ct][r] + a0, 0.f), s, a1);
                out[((long)(t0 + tt) * N + n0 + node) * 128 + c] = f2bf(v);
            }
        }
    }
}

// ============================ fused GCN layers 1/2 (t-PAIRED): agg(h bf16) + W GEMM + epi ====
// Block = 16 nodes x 2 t: one addr calc / metadata read serves two gathers (2x MLP).
// t-pair working set 5.1 MB over 2 XCDs' L2 (grid x=4 round-robins pairs over 8 XCDs).
template<int EPI>
__global__ __launch_bounds__(NTHREADS)
void gcn128_kernel(const u16* __restrict__ h, const int* __restrict__ rowptr,
                   const int2* __restrict__ epk,
                   const float* __restrict__ selfw, const u16* __restrict__ Wt,
                   const float* __restrict__ bias,
                   const float* __restrict__ bng, const float* __restrict__ bnb,
                   const float* __restrict__ bnm, const float* __restrict__ bnv,
                   u16* __restrict__ out, int N) {
    constexpr int ASTR = 136;
    constexpr int ECAP = 1024;
    __shared__ __align__(16) u16 aT[2][16][ASTR];
    __shared__ int2 sM[ECAP];
    const int t0 = blockIdx.x * 2;
    const int n0 = blockIdx.y * 16;
    const int tid = threadIdx.x;
    const int wid = tid >> 6, lane = tid & 63;
    const int quad = lane >> 4, l16 = lane & 15;
    const u16* hb0 = h + (long)t0 * N * 128;
    const u16* hb1 = hb0 + (long)N * 128;

    const int eb0 = rowptr[n0];
    const int ecnt = min(rowptr[n0 + 16] - eb0, ECAP);
    for (int p = tid; p < ecnt; p += NTHREADS) sM[p] = epk[eb0 + p];
    __syncthreads();

    // ---- phase A: aggregate 4 nodes per wave (4 splits x 16 lanes x 8ch x 2t) ----
    const int split = lane >> 4;                  // 0..3
    const int c8 = l16 * 8;
    for (int i = 0; i < 4; ++i) {
        const int n = n0 + wid * 4 + i;
        const int l0 = rowptr[n] - eb0;
        const int l1 = rowptr[n + 1] - eb0;
        const int eL = min(l1, ecnt);
        const int start = l0 + split;
        float2_t aA[4] = {(float2_t){0.f, 0.f}, (float2_t){0.f, 0.f},
                          (float2_t){0.f, 0.f}, (float2_t){0.f, 0.f}};
        float2_t aB[4] = {(float2_t){0.f, 0.f}, (float2_t){0.f, 0.f},
                          (float2_t){0.f, 0.f}, (float2_t){0.f, 0.f}};
        #pragma unroll 4
        for (int e = start; e < eL; e += 4) {
            const int2 m = sM[e];
            const float w = __int_as_float(m.y);
            const float2_t w2 = {w, w};
            const long o = (long)m.x * 128 + c8;
            const uint4 v0 = *(const uint4*)(hb0 + o);
            const uint4 v1 = *(const uint4*)(hb1 + o);
            aA[0] = __builtin_elementwise_fma(bfpair(v0.x), w2, aA[0]);
            aA[1] = __builtin_elementwise_fma(bfpair(v0.y), w2, aA[1]);
            aA[2] = __builtin_elementwise_fma(bfpair(v0.z), w2, aA[2]);
            aA[3] = __builtin_elementwise_fma(bfpair(v0.w), w2, aA[3]);
            aB[0] = __builtin_elementwise_fma(bfpair(v1.x), w2, aB[0]);
            aB[1] = __builtin_elementwise_fma(bfpair(v1.y), w2, aB[1]);
            aB[2] = __builtin_elementwise_fma(bfpair(v1.z), w2, aB[2]);
            aB[3] = __builtin_elementwise_fma(bfpair(v1.w), w2, aB[3]);
        }
        // overflow tail (statistically never taken)
        const int kL = (eL > start) ? (eL - start + 3) >> 2 : 0;
        for (int e = start + kL * 4; e < l1; e += 4) {
            const int2 m = epk[eb0 + e];
            const float w = __int_as_float(m.y);
            const float2_t w2 = {w, w};
            const long o = (long)m.x * 128 + c8;
            const uint4 v0 = *(const uint4*)(hb0 + o);
            const uint4 v1 = *(const uint4*)(hb1 + o);
            aA[0] = __builtin_elementwise_fma(bfpair(v0.x), w2, aA[0]);
            aA[1] = __builtin_elementwise_fma(bfpair(v0.y), w2, aA[1]);
            aA[2] = __builtin_elementwise_fma(bfpair(v0.z), w2, aA[2]);
            aA[3] = __builtin_elementwise_fma(bfpair(v0.w), w2, aA[3]);
            aB[0] = __builtin_elementwise_fma(bfpair(v1.x), w2, aB[0]);
            aB[1] = __builtin_elementwise_fma(bfpair(v1.y), w2, aB[1]);
            aB[2] = __builtin_elementwise_fma(bfpair(v1.z), w2, aB[2]);
            aB[3] = __builtin_elementwise_fma(bfpair(v1.w), w2, aB[3]);
        }
        float a[16] = {aA[0][0], aA[0][1], aA[1][0], aA[1][1],
                       aA[2][0], aA[2][1], aA[3][0], aA[3][1],
                       aB[0][0], aB[0][1], aB[1][0], aB[1][1],
                       aB[2][0], aB[2][1], aB[3][0], aB[3][1]};
        #pragma unroll
        for (int j = 0; j < 16; ++j) {
            a[j] += __shfl_xor(a[j], 16);
            a[j] += __shfl_xor(a[j], 32);
        }
        if (split == 0) {
            const float sw = selfw[n];
            const uint4 s0 = *(const uint4*)(hb0 + (long)n * 128 + c8);
            const uint4 s1 = *(const uint4*)(hb1 + (long)n * 128 + c8);
            float f0[8], f1[8];
            bf8_unpack(s0, f0);
            bf8_unpack(s1, f1);
            ushort4 oA0, oA1, oB0, oB1;
            oA0.x = f2bf(fmaf(sw, f0[0], a[0]));  oA0.y = f2bf(fmaf(sw, f0[1], a[1]));
            oA0.z = f2bf(fmaf(sw, f0[2], a[2]));  oA0.w = f2bf(fmaf(sw, f0[3], a[3]));
            oA1.x = f2bf(fmaf(sw, f0[4], a[4]));  oA1.y = f2bf(fmaf(sw, f0[5], a[5]));
            oA1.z = f2bf(fmaf(sw, f0[6], a[6]));  oA1.w = f2bf(fmaf(sw, f0[7], a[7]));
            oB0.x = f2bf(fmaf(sw, f1[0], a[8]));  oB0.y = f2bf(fmaf(sw, f1[1], a[9]));
            oB0.z = f2bf(fmaf(sw, f1[2], a[10])); oB0.w = f2bf(fmaf(sw, f1[3], a[11]));
            oB1.x = f2bf(fmaf(sw, f1[4], a[12])); oB1.y = f2bf(fmaf(sw, f1[5], a[13]));
            oB1.z = f2bf(fmaf(sw, f1[6], a[14])); oB1.w = f2bf(fmaf(sw, f1[7], a[15]));
            *(ushort4*)(&aT[0][wid * 4 + i][c8]) = oA0;
            *(ushort4*)(&aT[0][wid * 4 + i][c8 + 4]) = oA1;
            *(ushort4*)(&aT[1][wid * 4 + i][c8]) = oB0;
            *(ushort4*)(&aT[1][wid * 4 + i][c8 + 4]) = oB1;
        }
    }
    __syncthreads();

    // ---- phase B: two [16][128]@Wt^T GEMMs; wave owns 32 cols, K=128 ----
    short8_t fA0[4], fA1[4];
    #pragma unroll
    for (int ks = 0; ks < 4; ++ks) {
        fA0[ks] = *(const short8_t*)(&aT[0][l16][ks * 32 + quad * 8]);
        fA1[ks] = *(const short8_t*)(&aT[1][l16][ks * 32 + quad * 8]);
    }
    float4_t acc[2][2];
    #pragma unroll
    for (int tt = 0; tt < 2; ++tt)
        #pragma unroll
        for (int ct = 0; ct < 2; ++ct) acc[tt][ct] = (float4_t){0.f, 0.f, 0.f, 0.f};
    #pragma unroll
    for (int ct = 0; ct < 2; ++ct) {
        const int col = wid * 32 + ct * 16 + l16;
        #pragma unroll
        for (int ks = 0; ks < 4; ++ks) {
            const short8_t fB = *(const short8_t*)(Wt + (long)col * 128 + ks * 32 + quad * 8);
            acc[0][ct] = __builtin_amdgcn_mfma_f32_16x16x32_bf16(fA0[ks], fB, acc[0][ct], 0, 0, 0);
            acc[1][ct] = __builtin_amdgcn_mfma_f32_16x16x32_bf16(fA1[ks], fB, acc[1][ct], 0, 0, 0);
        }
    }

    #pragma unroll
    for (int ct = 0; ct < 2; ++ct) {
        const int c = wid * 32 + ct * 16 + l16;
        const float a0 = bias[c];
        float s = 0.f, a1 = 0.f;
        if constexpr (EPI == 2) {
            s = bng[c] * rsqrtf(bnv[c] + 1e-5f);
            a1 = bnb[c] - bnm[c] * s;
        }
        #pragma unroll
        for (int tt = 0; tt < 2; ++tt) {
            #pragma unroll
            for (int r = 0; r < 4; ++r) {
                const int node = quad * 4 + r;
                float v = fmaxf(acc[tt][ct][r] + a0, 0.f);
                if constexpr (EPI == 2) v = fmaf(v, s, a1);
                out[((long)(t0 + tt) * N + n0 + node) * 128 + c] = f2bf(v);
            }
        }
    }
}

// ============================ LSTM layer 0 (KIN=128, writes hi/lo planes) ============================
__global__ __launch_bounds__(NTHREADS, 2)
void lstm0_kernel(const u16* __restrict__ in_h, const u16* __restrict__ wih,
                  const u16* __restrict__ whh,
                  const float* __restrict__ bi, const float* __restrict__ bh,
                  u16* __restrict__ out_hi, u16* __restrict__ out_lo, int N) {
    constexpr int HSTR = 76;
    const int tid = threadIdx.x;
    const int w = tid >> 6, lane = tid & 63;
    const int quad = lane >> 4, l16 = lane & 15;
    const int n0 = blockIdx.x * 16;
    const int u = w * 16 + l16;

    __shared__ __align__(16) u16 hT[2][16][HSTR];
    for (int p = tid; p < 2 * 16 * HSTR; p += NTHREADS) (&hT[0][0][0])[p] = 0;

    short8_t fI[4][4], fH[4][2];
    #pragma unroll
    for (int g = 0; g < 4; ++g) {
        #pragma unroll
        for (int ks = 0; ks < 4; ++ks)
            fI[g][ks] = *(const short8_t*)(wih + (long)(g * 64 + u) * 128 + ks * 32 + quad * 8);
        #pragma unroll
        for (int ks = 0; ks < 2; ++ks)
            fH[g][ks] = *(const short8_t*)(whh + (long)(g * 64 + u) * 64 + ks * 32 + quad * 8);
    }
    float bias[4];
    #pragma unroll
    for (int g = 0; g < 4; ++g) bias[g] = bi[g * 64 + u] + bh[g * 64 + u];
    float cst[4] = {};
    __syncthreads();

    #pragma unroll 1
    for (int t = 0; t < T_STEPS; ++t) {
        short8_t ain[4];
        const long ibase = ((long)t * N + n0 + l16) * 128 + quad * 8;
        #pragma unroll
        for (int ks = 0; ks < 4; ++ks)
            ain[ks] = *(const short8_t*)(in_h + ibase + ks * 32);
        short8_t ah[2], al[2];
        #pragma unroll
        for (int ks = 0; ks < 2; ++ks) {
            ah[ks] = *(const short8_t*)(&hT[0][l16][ks * 32 + quad * 8]);
            al[ks] = *(const short8_t*)(&hT[1][l16][ks * 32 + quad * 8]);
        }
        __syncthreads();

        float4_t acc[4];
        #pragma unroll
        for (int g = 0; g < 4; ++g) acc[g] = (float4_t){bias[g], bias[g], bias[g], bias[g]};
        #pragma unroll
        for (int ks = 0; ks < 4; ++ks)
            #pragma unroll
            for (int g = 0; g < 4; ++g)
                acc[g] = __builtin_amdgcn_mfma_f32_16x16x32_bf16(ain[ks], fI[g][ks], acc[g], 0, 0, 0);
        #pragma unroll
        for (int ks = 0; ks < 2; ++ks)
            #pragma unroll
            for (int g = 0; g < 4; ++g) {
                acc[g] = __builtin_amdgcn_mfma_f32_16x16x32_bf16(ah[ks], fH[g][ks], acc[g], 0, 0, 0);
                acc[g] = __builtin_amdgcn_mfma_f32_16x16x32_bf16(al[ks], fH[g][ks], acc[g], 0, 0, 0);
            }

        #pragma unroll
        for (int r = 0; r < 4; ++r) {
            const float si = fsig(acc[0][r]);
            const float sf = fsig(acc[1][r]);
            const float gg = ftanh(acc[2][r]);
            const float so = fsig(acc[3][r]);
            const float c = sf * cst[r] + si * gg;
            cst[r] = c;
            const float h = so * ftanh(c);
            const int node = quad * 4 + r;
            const u16 hi = f2bf(h);
            const u16 lo = f2bf(h - bf2f(hi));
            hT[0][node][u] = hi;
            hT[1][node][u] = lo;
            const long o = ((long)t * N + n0 + node) * 64 + u;
            out_hi[o] = hi;
            out_lo[o] = lo;
        }
        __syncthreads();
    }
}

// ============================ fused LSTM layers 1+2 ============================
// Layer 2 consumes layer 1's h directly from LDS (hi/lo) -> no intermediate planes.
__global__ __launch_bounds__(NTHREADS)
void lstm12_kernel(const u16* __restrict__ in_hi, const u16* __restrict__ in_lo,
                   const u16* __restrict__ wih1, const u16* __restrict__ whh1,
                   const u16* __restrict__ wih2, const u16* __restrict__ whh2,
                   const float* __restrict__ bi1, const float* __restrict__ bh1,
                   const float* __restrict__ bi2, const float* __restrict__ bh2,
                   float* __restrict__ out_f, int N) {
    constexpr int HSTR = 76;
    const int tid = threadIdx.x;
    const int w = tid >> 6, lane = tid & 63;
    const int quad = lane >> 4, l16 = lane & 15;
    const int n0 = blockIdx.x * 16;
    const int u = w * 16 + l16;

    __shared__ __align__(16) u16 hT[2][2][16][HSTR];   // [layer][hi/lo][node][unit]
    for (int p = tid; p < 2 * 2 * 16 * HSTR; p += NTHREADS) (&hT[0][0][0][0])[p] = 0;

    short8_t fI1[4][2], fH1[4][2], fI2[4][2], fH2[4][2];
    #pragma unroll
    for (int g = 0; g < 4; ++g)
        #pragma unroll
        for (int ks = 0; ks < 2; ++ks) {
            fI1[g][ks] = *(const short8_t*)(wih1 + (long)(g * 64 + u) * 64 + ks * 32 + quad * 8);
            fH1[g][ks] = *(const short8_t*)(whh1 + (long)(g * 64 + u) * 64 + ks * 32 + quad * 8);
            fI2[g][ks] = *(const short8_t*)(wih2 + (long)(g * 64 + u) * 64 + ks * 32 + quad * 8);
            fH2[g][ks] = *(const short8_t*)(whh2 + (long)(g * 64 + u) * 64 + ks * 32 + quad * 8);
        }
    float b1[4], b2[4];
    #pragma unroll
    for (int g = 0; g < 4; ++g) {
        b1[g] = bi1[g * 64 + u] + bh1[g * 64 + u];
        b2[g] = bi2[g * 64 + u] + bh2[g * 64 + u];
    }
    float c1[4] = {}, c2[4] = {};
    __syncthreads();

    #pragma unroll 1
    for (int t = 0; t < T_STEPS; ++t) {
        // S0: read all (t-1) recurrent frags + layer-1 global input
        short8_t ainh[2], ainl[2], r1h[2], r1l[2], r2h[2], r2l[2];
        const long ibase = ((long)t * N + n0 + l16) * 64 + quad * 8;
        #pragma unroll
        for (int ks = 0; ks < 2; ++ks) {
            ainh[ks] = *(const short8_t*)(in_hi + ibase + ks * 32);
            ainl[ks] = *(const short8_t*)(in_lo + ibase + ks * 32);
            r1h[ks] = *(const short8_t*)(&hT[0][0][l16][ks * 32 + quad * 8]);
            r1l[ks] = *(const short8_t*)(&hT[0][1][l16][ks * 32 + quad * 8]);
            r2h[ks] = *(const short8_t*)(&hT[1][0][l16][ks * 32 + quad * 8]);
            r2l[ks] = *(const short8_t*)(&hT[1][1][l16][ks * 32 + quad * 8]);
        }
        __syncthreads();               // (t-1) reads done before overwrite

        // ---- layer 1 ----
        float4_t acc[4];
        #pragma unroll
        for (int g = 0; g < 4; ++g) acc[g] = (float4_t){b1[g], b1[g], b1[g], b1[g]};
        #pragma unroll
        for (int ks = 0; ks < 2; ++ks)
            #pragma unroll
            for (int g = 0; g < 4; ++g) {
                acc[g] = __builtin_amdgcn_mfma_f32_16x16x32_bf16(ainh[ks], fI1[g][ks], acc[g], 0, 0, 0);
                acc[g] = __builtin_amdgcn_mfma_f32_16x16x32_bf16(ainl[ks], fI1[g][ks], acc[g], 0, 0, 0);
                acc[g] = __builtin_amdgcn_mfma_f32_16x16x32_bf16(r1h[ks], fH1[g][ks], acc[g], 0, 0, 0);
                acc[g] = __builtin_amdgcn_mfma_f32_16x16x32_bf16(r1l[ks], fH1[g][ks], acc[g], 0, 0, 0);
            }
        #pragma unroll
        for (int r = 0; r < 4; ++r) {
            const float si = fsig(acc[0][r]);
            const float sf = fsig(acc[1][r]);
            const float gg = ftanh(acc[2][r]);
            const float so = fsig(acc[3][r]);
            const float c = sf * c1[r] + si * gg;
            c1[r] = c;
            const float h = so * ftanh(c);
            const int node = quad * 4 + r;
            const u16 hi = f2bf(h);
            hT[0][0][node][u] = hi;
            hT[0][1][node][u] = f2bf(h - bf2f(hi));
        }
        __syncthreads();               // h1(t) visible

        // ---- layer 2 (input = h1(t) from LDS) ----
        short8_t i2h[2], i2l[2];
        #pragma unroll
        for (int ks = 0; ks < 2; ++ks) {
            i2h[ks] = *(const short8_t*)(&hT[0][0][l16][ks * 32 + quad * 8]);
            i2l[ks] = *(const short8_t*)(&hT[0][1][l16][ks * 32 + quad * 8]);
        }
        #pragma unroll
        for (int g = 0; g < 4; ++g) acc[g] = (float4_t){b2[g], b2[g], b2[g], b2[g]};
        #pragma unroll
        for (int ks = 0; ks < 2; ++ks)
            #pragma unroll
            for (int g = 0; g < 4; ++g) {
                acc[g] = __builtin_amdgcn_mfma_f32_16x16x32_bf16(i2h[ks], fI2[g][ks], acc[g], 0, 0, 0);
                acc[g] = __builtin_amdgcn_mfma_f32_16x16x32_bf16(i2l[ks], fI2[g][ks], acc[g], 0, 0, 0);
                acc[g] = __builtin_amdgcn_mfma_f32_16x16x32_bf16(r2h[ks], fH2[g][ks], acc[g], 0, 0, 0);
                acc[g] = __builtin_amdgcn_mfma_f32_16x16x32_bf16(r2l[ks], fH2[g][ks], acc[g], 0, 0, 0);
            }
        #pragma unroll
        for (int r = 0; r < 4; ++r) {
            const float si = fsig(acc[0][r]);
            const float sf = fsig(acc[1][r]);
            const float gg = ftanh(acc[2][r]);
            const float so = fsig(acc[3][r]);
            const float c = sf * c2[r] + si * gg;
            c2[r] = c;
            const float h = so * ftanh(c);
            const int node = quad * 4 + r;
            if (t == T_STEPS - 1) {
                out_f[(long)(n0 + node) * 64 + u] = h;
            } else {
                const u16 hi = f2bf(h);
                hT[1][0][node][u] = hi;
                hT[1][1][node][u] = f2bf(h - bf2f(hi));
            }
        }
        __syncthreads();               // h2(t) visible for next-t S0 reads
    }
}

// ============================ launch ============================
extern "C" void kernel_launch(void* const* d_in, const int* in_sizes, int n_in,
                              void* d_out, int out_size, void* d_ws, size_t ws_size,
                              hipStream_t stream) {
    (void)n_in; (void)out_size; (void)ws_size;
    const float* x      = (const float*)d_in[0];
    const int*   ei     = (const int*)d_in[1];
    const float* w_gcn0 = (const float*)d_in[2];
    const float* b_gcn0 = (const float*)d_in[3];
    const float* w_gcn1 = (const float*)d_in[4];
    const float* b_gcn1 = (const float*)d_in[5];
    const float* w_gcn2 = (const float*)d_in[6];
    const float* b_gcn2 = (const float*)d_in[7];
    const float* bn_g0  = (const float*)d_in[8];
    const float* bn_b0  = (const float*)d_in[9];
    const float* bn_m0  = (const float*)d_in[10];
    const float* bn_v0  = (const float*)d_in[11];
    const float* bn_g1  = (const float*)d_in[12];
    const float* bn_b1  = (const float*)d_in[13];
    const float* bn_m1  = (const float*)d_in[14];
    const float* bn_v1  = (const float*)d_in[15];
    const float* w_ih_0 = (const float*)d_in[16];
    const float* w_hh_0 = (const float*)d_in[17];
    const float* b_ih_0 = (const float*)d_in[18];
    const float* b_hh_0 = (const float*)d_in[19];
    const float* w_ih_1 = (const float*)d_in[20];
    const float* w_hh_1 = (const float*)d_in[21];
    const float* b_ih_1 = (const float*)d_in[22];
    const float* b_hh_1 = (const float*)d_in[23];
    const float* w_ih_2 = (const float*)d_in[24];
    const float* w_hh_2 = (const float*)d_in[25];
    const float* b_ih_2 = (const float*)d_in[26];
    const float* b_hh_2 = (const float*)d_in[27];

    const int E = in_sizes[1] / 2;
    const int N = in_sizes[0] / (T_STEPS * F_INC);     // 10000
    const long M = (long)N * T_STEPS;                  // 80000

    char* ws = (char*)d_ws;
    size_t off = 0;
    auto carve = [&](size_t bytes) -> void* {
        void* p = ws + off;
        off += (bytes + 255) & ~(size_t)255;
        return p;
    };
    float* dis     = (float*)carve((size_t)N * 4);
    float* selfw   = (float*)carve((size_t)N * 4);
    int*   cnt     = (int*)carve((size_t)N * 4);
    int*   rowptr  = (int*)carve((size_t)(N + 1) * 4);
    int*   wp      = (int*)carve((size_t)N * 4);
    int2*  epk     = (int2*)carve((size_t)E * 8);
    int*   bsum    = (int*)carve(64 * 4);
    u16*   hbuf    = (u16*)carve((size_t)M * H_DIM * 2);      // 20.5 MB, [t][n][128]
    u16*   hbuf2   = (u16*)carve((size_t)M * H_DIM * 2);      // 20.5 MB ping-pong
    u16*   pA_hi   = (u16*)carve((size_t)M * O_DIM * 2);
    u16*   pA_lo   = (u16*)carve((size_t)M * O_DIM * 2);
    u16*   wt0     = (u16*)carve((size_t)128 * 32 * 2);
    u16*   wt1     = (u16*)carve((size_t)128 * 128 * 2);
    u16*   wt2     = (u16*)carve((size_t)128 * 128 * 2);
    u16*   wtih0   = (u16*)carve((size_t)256 * 128 * 2);
    u16*   wtih1   = (u16*)carve((size_t)256 * 64 * 2);
    u16*   wtih2   = (u16*)carve((size_t)256 * 64 * 2);
    u16*   whh0b   = (u16*)carve((size_t)256 * 64 * 2);
    u16*   whh1b   = (u16*)carve((size_t)256 * 64 * 2);
    u16*   whh2b   = (u16*)carve((size_t)256 * 64 * 2);

    const dim3 b256(NTHREADS);
    const int gN = (N + NTHREADS - 1) / NTHREADS;      // 40
    const int gE = (E + NTHREADS - 1) / NTHREADS;      // 782

    // ---- CSR + weight prep ----
    hipMemsetAsync(cnt, 0, (size_t)N * 4, stream);
    count_wprep_kernel<<<gE + (151552 + 255) / 256, b256, 0, stream>>>(
        ei, cnt, E, gE,
        w_gcn0, w_gcn1, w_gcn2, w_ih_0, w_ih_1, w_ih_2, w_hh_0, w_hh_1, w_hh_2,
        wt0, wt1, wt2, wtih0, wtih1, wtih2, whh0b, whh1b, whh2b);
    scan_part1<<<gN, b256, 0, stream>>>(cnt, bsum, N);
    scan_part3<<<gN, b256, 0, stream>>>(cnt, bsum, rowptr, wp, dis, selfw, N);
    fill_kernel<<<gE, b256, 0, stream>>>(ei, dis, wp, epk, E);

    // ---- GCN: fused agg+GEMM per layer (t-paired, LDS edge staging) ----
    const dim3 gG(T_STEPS / 2, N / 16);                 // (4, 625)
    gcn32_kernel<<<gG, b256, 0, stream>>>(
        x, rowptr, epk, selfw, wt0, b_gcn0,
        bn_g0, bn_b0, bn_m0, bn_v0, hbuf, N);
    gcn128_kernel<2><<<gG, b256, 0, stream>>>(
        hbuf, rowptr, epk, selfw, wt1, b_gcn1,
        bn_g1, bn_b1, bn_m1, bn_v1, hbuf2, N);
    gcn128_kernel<1><<<gG, b256, 0, stream>>>(
        hbuf2, rowptr, epk, selfw, wt2, b_gcn2,
        nullptr, nullptr, nullptr, nullptr, hbuf, N);

    // ---- LSTM: layer0 + fused layers 1+2 ----
    const int gL = N / 16;             // 625
    lstm0_kernel<<<gL, b256, 0, stream>>>(
        hbuf, wtih0, whh0b, b_ih_0, b_hh_0, pA_hi, pA_lo, N);
    lstm12_kernel<<<gL, b256, 0, stream>>>(
        pA_hi, pA_lo, wtih1, whh1b, wtih2, whh2b,
        b_ih_1, b_hh_1, b_ih_2, b_hh_2, (float*)d_out, N);
}

// Round 10
// 354.427 us; speedup vs baseline: 1.0263x; 1.0263x over previous
//
#include <hip/hip_runtime.h>
#include <hip/hip_bf16.h>
#include <math.h>

#define NTHREADS 256
#define T_STEPS 8
#define F_INC 32
#define H_DIM 128
#define O_DIM 64

typedef unsigned short u16;
typedef __attribute__((ext_vector_type(8))) short short8_t;
typedef __attribute__((ext_vector_type(4))) float float4_t;
typedef __attribute__((ext_vector_type(2))) float float2_t;

__device__ __forceinline__ float bf2f(u16 u) {
    return __uint_as_float(((unsigned)u) << 16);
}
__device__ __forceinline__ u16 f2bf(float f) {
    __hip_bfloat16 h = __float2bfloat16(f);   // RNE
    union { __hip_bfloat16 h; u16 s; } cv; cv.h = h; return cv.s;
}
// one dword (2 bf16) -> float2 {lo, hi}
__device__ __forceinline__ float2_t bfpair(unsigned u) {
    union { unsigned w[2]; float2_t f; } c;
    c.w[0] = u << 16;
    c.w[1] = u & 0xffff0000u;
    return c.f;
}
__device__ __forceinline__ void bf8_unpack(uint4 u, float* f) {
    f[0] = __uint_as_float(u.x << 16); f[1] = __uint_as_float(u.x & 0xffff0000u);
    f[2] = __uint_as_float(u.y << 16); f[3] = __uint_as_float(u.y & 0xffff0000u);
    f[4] = __uint_as_float(u.z << 16); f[5] = __uint_as_float(u.z & 0xffff0000u);
    f[6] = __uint_as_float(u.w << 16); f[7] = __uint_as_float(u.w & 0xffff0000u);
}
// fast sigmoid/tanh via v_exp_f32 (~1ulp, << bf16 noise)
__device__ __forceinline__ float fsig(float x) {
    float xc = fminf(fmaxf(x, -30.f), 30.f);
    float e = __builtin_amdgcn_exp2f(xc * -1.4426950408889634f);
    return __builtin_amdgcn_rcpf(1.0f + e);
}
__device__ __forceinline__ float ftanh(float x) {
    float xc = fminf(fmaxf(x, -15.f), 15.f);
    float e = __builtin_amdgcn_exp2f(xc * -2.8853900817779268f);
    float r = __builtin_amdgcn_rcpf(1.0f + e);
    return fmaf(-2.0f * e, r, 1.0f);
}

// ============================ CSR count + weight prep + x->bf16 (one launch) ============
// blocks [0,gE): edge count atomics; [gE, gE+592): weight prep; [gE+592, ...): x cast.
__global__ void count_wprep_kernel(const int* __restrict__ ei, int* __restrict__ cnt,
                                   int E, int gE, int NX,
                                   const float* __restrict__ x, u16* __restrict__ xb,
                                   const float* g0, const float* g1, const float* g2,
                                   const float* i0, const float* i1, const float* i2,
                                   const float* h0, const float* h1, const float* h2,
                                   u16* o_g0, u16* o_g1, u16* o_g2,
                                   u16* o_i0, u16* o_i1, u16* o_i2,
                                   u16* o_h0, u16* o_h1, u16* o_h2) {
    if ((int)blockIdx.x < gE) {
        int e = blockIdx.x * NTHREADS + threadIdx.x;
        if (e < E) atomicAdd(&cnt[ei[E + e]], 1);   // dst row of edge_index
        return;
    }
    if ((int)blockIdx.x < gE + 592) {
        const int i = (blockIdx.x - gE) * NTHREADS + threadIdx.x;
        if (i < 4096)        { o_g0[i] = f2bf(g0[(i & 31) * 128 + (i >> 5)]); }
        else if (i < 20480)  { int j = i - 4096;   o_g1[j] = f2bf(g1[(j & 127) * 128 + (j >> 7)]); }
        else if (i < 36864)  { int j = i - 20480;  o_g2[j] = f2bf(g2[(j & 127) * 128 + (j >> 7)]); }
        else if (i < 69632)  { int j = i - 36864;  o_i0[j] = f2bf(i0[j]); }
        else if (i < 86016)  { int j = i - 69632;  o_i1[j] = f2bf(i1[j]); }
        else if (i < 102400) { int j = i - 86016;  o_i2[j] = f2bf(i2[j]); }
        else if (i < 118784) { int j = i - 102400; o_h0[j] = f2bf(h0[j]); }
        else if (i < 135168) { int j = i - 118784; o_h1[j] = f2bf(h1[j]); }
        else if (i < 151552) { int j = i - 135168; o_h2[j] = f2bf(h2[j]); }
        return;
    }
    // x [t][n][32] fp32 -> xb same layout bf16 (flat cast, vector 4)
    const long i4 = ((long)(blockIdx.x - gE - 592) * NTHREADS + threadIdx.x) * 4;
    if (i4 < (long)NX) {
        const float4 v = *(const float4*)(x + i4);
        ushort4 o;
        o.x = f2bf(v.x); o.y = f2bf(v.y); o.z = f2bf(v.z); o.w = f2bf(v.w);
        *(ushort4*)(xb + i4) = o;
    }
}

__global__ void scan_part1(const int* __restrict__ cnt, int* __restrict__ bsum, int n) {
    __shared__ int sd[NTHREADS];
    const int i = blockIdx.x * NTHREADS + threadIdx.x;
    sd[threadIdx.x] = (i < n) ? cnt[i] : 0;
    __syncthreads();
    for (int off = 128; off > 0; off >>= 1) {
        if (threadIdx.x < off) sd[threadIdx.x] += sd[threadIdx.x + off];
        __syncthreads();
    }
    if (threadIdx.x == 0) bsum[blockIdx.x] = sd[0];
}

// inlined block-offset (wave shuffle over bsum) + scan + dis/selfw
__global__ void scan_part3(const int* __restrict__ cnt, const int* __restrict__ bsum,
                           int* __restrict__ rowptr, int* __restrict__ wp,
                           float* __restrict__ dis, float* __restrict__ selfw, int n) {
    __shared__ int sd[NTHREADS];
    __shared__ int sbase;
    const int tid = threadIdx.x;
    if (tid < 64) {
        int v0 = (tid < blockIdx.x) ? bsum[tid] : 0;   // nb <= 64
        #pragma unroll
        for (int off = 1; off < 64; off <<= 1) v0 += __shfl_xor(v0, off);
        if (tid == 0) sbase = v0;
    }
    const int i = blockIdx.x * NTHREADS + tid;
    const int v = (i < n) ? cnt[i] : 0;
    sd[tid] = v;
    __syncthreads();
    for (int off = 1; off < NTHREADS; off <<= 1) {
        const int tv = (tid >= off) ? sd[tid - off] : 0;
        __syncthreads();
        sd[tid] += tv;
        __syncthreads();
    }
    const int excl = sbase + sd[tid] - v;
    if (i < n) {
        rowptr[i] = excl; wp[i] = excl;
        if (i == n - 1) rowptr[n] = excl + v;
        const float d = 1.0f + (float)v;
        dis[i] = rsqrtf(d);
        selfw[i] = 1.0f / d;
    }
}

// packed edge metadata: epk[p] = (src, coef) -> one 8B load per edge
__global__ void fill_kernel(const int* __restrict__ ei, const float* __restrict__ dis,
                            int* __restrict__ wp, int2* __restrict__ epk, int E) {
    int e = blockIdx.x * NTHREADS + threadIdx.x;
    if (e < E) {
        int s = ei[e], d = ei[E + e];
        int p = atomicAdd(&wp[d], 1);
        epk[p] = make_int2(s, __float_as_int(dis[s] * dis[d]));
    }
}

// ============================ fused GCN layer 0: agg(xb bf16) + W0 GEMM + BN ============================
// t-PAIRED: block = 16 nodes x 2 t; gathers now bf16 (64 B/edge-t = 1 sector).
__global__ __launch_bounds__(NTHREADS)
void gcn32_kernel(const u16* __restrict__ xb, const int* __restrict__ rowptr,
                  const int2* __restrict__ epk,
                  const float* __restrict__ selfw, const u16* __restrict__ Wt,
                  const float* __restrict__ bias,
                  const float* __restrict__ bng, const float* __restrict__ bnb,
                  const float* __restrict__ bnm, const float* __restrict__ bnv,
                  u16* __restrict__ out, int N) {
    constexpr int ASTR = 40;
    constexpr int ECAP = 1024;
    __shared__ __align__(16) u16 aT[2][16][ASTR];
    __shared__ int2 sM[ECAP];
    const int t0 = blockIdx.x * 2;
    const int n0 = blockIdx.y * 16;
    const int tid = threadIdx.x;
    const int wid = tid >> 6, lane = tid & 63;
    const int quad = lane >> 4, l16 = lane & 15;
    const u16* xb0 = xb + (long)t0 * N * 32;
    const u16* xb1 = xb0 + (long)N * 32;

    const int eb0 = rowptr[n0];
    const int ecnt = min(rowptr[n0 + 16] - eb0, ECAP);
    for (int p = tid; p < ecnt; p += NTHREADS) sM[p] = epk[eb0 + p];
    __syncthreads();

    // ---- phase A: aggregate 4 nodes per wave (8 splits x 8 lanes x 4ch x 2t) ----
    const int split = lane >> 3;                  // 0..7
    const int c4 = (lane & 7) * 4;
    for (int i = 0; i < 4; ++i) {
        const int n = n0 + wid * 4 + i;
        const int l0 = rowptr[n] - eb0;
        const int l1 = rowptr[n + 1] - eb0;
        const int eL = min(l1, ecnt);
        const int start = l0 + split;
        float2_t a0[2] = {(float2_t){0.f, 0.f}, (float2_t){0.f, 0.f}};
        float2_t a1[2] = {(float2_t){0.f, 0.f}, (float2_t){0.f, 0.f}};
        #pragma unroll 4
        for (int e = start; e < eL; e += 8) {
            const int2 m = sM[e];
            const float w = __int_as_float(m.y);
            const float2_t w2 = {w, w};
            const long o = (long)m.x * 32 + c4;
            const uint2 v0 = *(const uint2*)(xb0 + o);
            const uint2 v1 = *(const uint2*)(xb1 + o);
            a0[0] = __builtin_elementwise_fma(bfpair(v0.x), w2, a0[0]);
            a0[1] = __builtin_elementwise_fma(bfpair(v0.y), w2, a0[1]);
            a1[0] = __builtin_elementwise_fma(bfpair(v1.x), w2, a1[0]);
            a1[1] = __builtin_elementwise_fma(bfpair(v1.y), w2, a1[1]);
        }
        // overflow tail (statistically never taken)
        const int kL = (eL > start) ? (eL - start + 7) >> 3 : 0;
        for (int e = start + kL * 8; e < l1; e += 8) {
            const int2 m = epk[eb0 + e];
            const float w = __int_as_float(m.y);
            const float2_t w2 = {w, w};
            const long o = (long)m.x * 32 + c4;
            const uint2 v0 = *(const uint2*)(xb0 + o);
            const uint2 v1 = *(const uint2*)(xb1 + o);
            a0[0] = __builtin_elementwise_fma(bfpair(v0.x), w2, a0[0]);
            a0[1] = __builtin_elementwise_fma(bfpair(v0.y), w2, a0[1]);
            a1[0] = __builtin_elementwise_fma(bfpair(v1.x), w2, a1[0]);
            a1[1] = __builtin_elementwise_fma(bfpair(v1.y), w2, a1[1]);
        }
        float r[8] = {a0[0][0], a0[0][1], a0[1][0], a0[1][1],
                      a1[0][0], a1[0][1], a1[1][0], a1[1][1]};
        #pragma unroll
        for (int j = 0; j < 8; ++j) {
            r[j] += __shfl_xor(r[j], 8);
            r[j] += __shfl_xor(r[j], 16);
            r[j] += __shfl_xor(r[j], 32);
        }
        if (split == 0) {
            const float sw = selfw[n];
            const uint2 s0 = *(const uint2*)(xb0 + (long)n * 32 + c4);
            const uint2 s1 = *(const uint2*)(xb1 + (long)n * 32 + c4);
            const float2_t s0a = bfpair(s0.x), s0b = bfpair(s0.y);
            const float2_t s1a = bfpair(s1.x), s1b = bfpair(s1.y);
            ushort4 o0, o1;
            o0.x = f2bf(fmaf(sw, s0a[0], r[0])); o0.y = f2bf(fmaf(sw, s0a[1], r[1]));
            o0.z = f2bf(fmaf(sw, s0b[0], r[2])); o0.w = f2bf(fmaf(sw, s0b[1], r[3]));
            o1.x = f2bf(fmaf(sw, s1a[0], r[4])); o1.y = f2bf(fmaf(sw, s1a[1], r[5]));
            o1.z = f2bf(fmaf(sw, s1b[0], r[6])); o1.w = f2bf(fmaf(sw, s1b[1], r[7]));
            *(ushort4*)(&aT[0][wid * 4 + i][c4]) = o0;
            *(ushort4*)(&aT[1][wid * 4 + i][c4]) = o1;
        }
    }
    __syncthreads();

    // ---- phase B: two 16x128 GEMMs vs W0t; wave owns 32 cols ----
    const short8_t fA0 = *(const short8_t*)(&aT[0][l16][quad * 8]);
    const short8_t fA1 = *(const short8_t*)(&aT[1][l16][quad * 8]);
    float4_t acc[2][2];
    short8_t fB[2];
    #pragma unroll
    for (int ct = 0; ct < 2; ++ct) {
        const int col = wid * 32 + ct * 16 + l16;
        fB[ct] = *(const short8_t*)(Wt + (long)col * 32 + quad * 8);
        acc[0][ct] = (float4_t){0.f, 0.f, 0.f, 0.f};
        acc[1][ct] = (float4_t){0.f, 0.f, 0.f, 0.f};
    }
    #pragma unroll
    for (int ct = 0; ct < 2; ++ct) {
        acc[0][ct] = __builtin_amdgcn_mfma_f32_16x16x32_bf16(fA0, fB[ct], acc[0][ct], 0, 0, 0);
        acc[1][ct] = __builtin_amdgcn_mfma_f32_16x16x32_bf16(fA1, fB[ct], acc[1][ct], 0, 0, 0);
    }

    #pragma unroll
    for (int ct = 0; ct < 2; ++ct) {
        const int c = wid * 32 + ct * 16 + l16;
        const float s = bng[c] * rsqrtf(bnv[c] + 1e-5f);
        const float a1 = bnb[c] - bnm[c] * s;
        const float a0 = bias[c];
        #pragma unroll
        for (int tt = 0; tt < 2; ++tt) {
            #pragma unroll
            for (int r = 0; r < 4; ++r) {
                const int node = quad * 4 + r;
                float v = fmaf(fmaxf(acc[tt][ct][r] + a0, 0.f), s, a1);
                out[((long)(t0 + tt) * N + n0 + node) * 128 + c] = f2bf(v);
            }
        }
    }
}

// ============================ fused GCN layers 1/2 (single-t, R8 form): agg + GEMM + epi ====
// EPI: 1 = bias,ReLU ; 2 = bias,ReLU,BN.  Wt is [128col][128k] bf16. pk_fma float2.
template<int EPI>
__global__ __launch_bounds__(NTHREADS)
void gcn128_kernel(const u16* __restrict__ h, const int* __restrict__ rowptr,
                   const int2* __restrict__ epk,
                   const float* __restrict__ selfw, const u16* __restrict__ Wt,
                   const float* __restrict__ bias,
                   const float* __restrict__ bng, const float* __restrict__ bnb,
                   const float* __restrict__ bnm, const float* __restrict__ bnv,
                   u16* __restrict__ out, int N) {
    constexpr int ASTR = 136;
    constexpr int ECAP = 1024;
    __shared__ __align__(16) u16 aT[16][ASTR];
    __shared__ int2 sM[ECAP];
    const int t = blockIdx.x;
    const int n0 = blockIdx.y * 16;
    const int tid = threadIdx.x;
    const int wid = tid >> 6, lane = tid & 63;
    const int quad = lane >> 4, l16 = lane & 15;
    const u16* hb = h + (long)t * N * 128;

    const int eb0 = rowptr[n0];
    const int ecnt = min(rowptr[n0 + 16] - eb0, ECAP);
    for (int p = tid; p < ecnt; p += NTHREADS) sM[p] = epk[eb0 + p];
    __syncthreads();

    // ---- phase A: aggregate 4 nodes per wave (4 splits x 16 lanes x 8ch) ----
    const int split = lane >> 4;                  // 0..3
    const int c8 = l16 * 8;
    for (int i = 0; i < 4; ++i) {
        const int n = n0 + wid * 4 + i;
        const int l0 = rowptr[n] - eb0;
        const int l1 = rowptr[n + 1] - eb0;
        const int eL = min(l1, ecnt);
        const int start = l0 + split;
        float2_t a2[4] = {(float2_t){0.f, 0.f}, (float2_t){0.f, 0.f},
                          (float2_t){0.f, 0.f}, (float2_t){0.f, 0.f}};
        #pragma unroll 4
        for (int e = start; e < eL; e += 4) {
            const int2 m = sM[e];
            const float w = __int_as_float(m.y);
            const float2_t w2 = {w, w};
            const uint4 v = *(const uint4*)(hb + (long)m.x * 128 + c8);
            a2[0] = __builtin_elementwise_fma(bfpair(v.x), w2, a2[0]);
            a2[1] = __builtin_elementwise_fma(bfpair(v.y), w2, a2[1]);
            a2[2] = __builtin_elementwise_fma(bfpair(v.z), w2, a2[2]);
            a2[3] = __builtin_elementwise_fma(bfpair(v.w), w2, a2[3]);
        }
        // overflow tail (statistically never taken)
        const int kL = (eL > start) ? (eL - start + 3) >> 2 : 0;
        for (int e = start + kL * 4; e < l1; e += 4) {
            const int2 m = epk[eb0 + e];
            const float w = __int_as_float(m.y);
            const float2_t w2 = {w, w};
            const uint4 v = *(const uint4*)(hb + (long)m.x * 128 + c8);
            a2[0] = __builtin_elementwise_fma(bfpair(v.x), w2, a2[0]);
            a2[1] = __builtin_elementwise_fma(bfpair(v.y), w2, a2[1]);
            a2[2] = __builtin_elementwise_fma(bfpair(v.z), w2, a2[2]);
            a2[3] = __builtin_elementwise_fma(bfpair(v.w), w2, a2[3]);
        }
        float a[8] = {a2[0][0], a2[0][1], a2[1][0], a2[1][1],
                      a2[2][0], a2[2][1], a2[3][0], a2[3][1]};
        #pragma unroll
        for (int j = 0; j < 8; ++j) {
            a[j] += __shfl_xor(a[j], 16);
            a[j] += __shfl_xor(a[j], 32);
        }
        if (split == 0) {
            const float sw = selfw[n];
            const uint4 sv = *(const uint4*)(hb + (long)n * 128 + c8);
            float f[8];
            bf8_unpack(sv, f);
            ushort4 o0, o1;
            o0.x = f2bf(fmaf(sw, f[0], a[0])); o0.y = f2bf(fmaf(sw, f[1], a[1]));
            o0.z = f2bf(fmaf(sw, f[2], a[2])); o0.w = f2bf(fmaf(sw, f[3], a[3]));
            o1.x = f2bf(fmaf(sw, f[4], a[4])); o1.y = f2bf(fmaf(sw, f[5], a[5]));
            o1.z = f2bf(fmaf(sw, f[6], a[6])); o1.w = f2bf(fmaf(sw, f[7], a[7]));
            *(ushort4*)(&aT[wid * 4 + i][c8]) = o0;
            *(ushort4*)(&aT[wid * 4 + i][c8 + 4]) = o1;
        }
    }
    __syncthreads();

    // ---- phase B: [16][128] @ Wt^T -> [16][128]; wave owns 32 cols, K=128 ----
    short8_t fA[4];
    #pragma unroll
    for (int ks = 0; ks < 4; ++ks)
        fA[ks] = *(const short8_t*)(&aT[l16][ks * 32 + quad * 8]);
    float4_t acc[2];
    #pragma unroll
    for (int ct = 0; ct < 2; ++ct) acc[ct] = (float4_t){0.f, 0.f, 0.f, 0.f};
    #pragma unroll
    for (int ct = 0; ct < 2; ++ct) {
        const int col = wid * 32 + ct * 16 + l16;
        #pragma unroll
        for (int ks = 0; ks < 4; ++ks) {
            const short8_t fB = *(const short8_t*)(Wt + (long)col * 128 + ks * 32 + quad * 8);
            acc[ct] = __builtin_amdgcn_mfma_f32_16x16x32_bf16(fA[ks], fB, acc[ct], 0, 0, 0);
        }
    }

    #pragma unroll
    for (int ct = 0; ct < 2; ++ct) {
        const int c = wid * 32 + ct * 16 + l16;
        const float a0 = bias[c];
        float s = 0.f, a1 = 0.f;
        if constexpr (EPI == 2) {
            s = bng[c] * rsqrtf(bnv[c] + 1e-5f);
            a1 = bnb[c] - bnm[c] * s;
        }
        #pragma unroll
        for (int r = 0; r < 4; ++r) {
            const int node = quad * 4 + r;
            float v = fmaxf(acc[ct][r] + a0, 0.f);
            if constexpr (EPI == 2) v = fmaf(v, s, a1);
            out[((long)t * N + n0 + node) * 128 + c] = f2bf(v);
        }
    }
}

// ============================ LSTM layer 0 (KIN=128, writes hi/lo planes) ============================
__global__ __launch_bounds__(NTHREADS, 2)
void lstm0_kernel(const u16* __restrict__ in_h, const u16* __restrict__ wih,
                  const u16* __restrict__ whh,
                  const float* __restrict__ bi, const float* __restrict__ bh,
                  u16* __restrict__ out_hi, u16* __restrict__ out_lo, int N) {
    constexpr int HSTR = 76;
    const int tid = threadIdx.x;
    const int w = tid >> 6, lane = tid & 63;
    const int quad = lane >> 4, l16 = lane & 15;
    const int n0 = blockIdx.x * 16;
    const int u = w * 16 + l16;

    __shared__ __align__(16) u16 hT[2][16][HSTR];
    for (int p = tid; p < 2 * 16 * HSTR; p += NTHREADS) (&hT[0][0][0])[p] = 0;

    short8_t fI[4][4], fH[4][2];
    #pragma unroll
    for (int g = 0; g < 4; ++g) {
        #pragma unroll
        for (int ks = 0; ks < 4; ++ks)
            fI[g][ks] = *(const short8_t*)(wih + (long)(g * 64 + u) * 128 + ks * 32 + quad * 8);
        #pragma unroll
        for (int ks = 0; ks < 2; ++ks)
            fH[g][ks] = *(const short8_t*)(whh + (long)(g * 64 + u) * 64 + ks * 32 + quad * 8);
    }
    float bias[4];
    #pragma unroll
    for (int g = 0; g < 4; ++g) bias[g] = bi[g * 64 + u] + bh[g * 64 + u];
    float cst[4] = {};
    __syncthreads();

    #pragma unroll 1
    for (int t = 0; t < T_STEPS; ++t) {
        short8_t ain[4];
        const long ibase = ((long)t * N + n0 + l16) * 128 + quad * 8;
        #pragma unroll
        for (int ks = 0; ks < 4; ++ks)
            ain[ks] = *(const short8_t*)(in_h + ibase + ks * 32);
        short8_t ah[2], al[2];
        #pragma unroll
        for (int ks = 0; ks < 2; ++ks) {
            ah[ks] = *(const short8_t*)(&hT[0][l16][ks * 32 + quad * 8]);
            al[ks] = *(const short8_t*)(&hT[1][l16][ks * 32 + quad * 8]);
        }
        __syncthreads();

        float4_t acc[4];
        #pragma unroll
        for (int g = 0; g < 4; ++g) acc[g] = (float4_t){bias[g], bias[g], bias[g], bias[g]};
        #pragma unroll
        for (int ks = 0; ks < 4; ++ks)
            #pragma unroll
            for (int g = 0; g < 4; ++g)
                acc[g] = __builtin_amdgcn_mfma_f32_16x16x32_bf16(ain[ks], fI[g][ks], acc[g], 0, 0, 0);
        #pragma unroll
        for (int ks = 0; ks < 2; ++ks)
            #pragma unroll
            for (int g = 0; g < 4; ++g) {
                acc[g] = __builtin_amdgcn_mfma_f32_16x16x32_bf16(ah[ks], fH[g][ks], acc[g], 0, 0, 0);
                acc[g] = __builtin_amdgcn_mfma_f32_16x16x32_bf16(al[ks], fH[g][ks], acc[g], 0, 0, 0);
            }

        #pragma unroll
        for (int r = 0; r < 4; ++r) {
            const float si = fsig(acc[0][r]);
            const float sf = fsig(acc[1][r]);
            const float gg = ftanh(acc[2][r]);
            const float so = fsig(acc[3][r]);
            const float c = sf * cst[r] + si * gg;
            cst[r] = c;
            const float h = so * ftanh(c);
            const int node = quad * 4 + r;
            const u16 hi = f2bf(h);
            const u16 lo = f2bf(h - bf2f(hi));
            hT[0][node][u] = hi;
            hT[1][node][u] = lo;
            const long o = ((long)t * N + n0 + node) * 64 + u;
            out_hi[o] = hi;
            out_lo[o] = lo;
        }
        __syncthreads();
    }
}

// ============================ fused LSTM layers 1+2 ============================
// Layer 2 consumes layer 1's h directly from LDS (hi/lo) -> no intermediate planes.
__global__ __launch_bounds__(NTHREADS)
void lstm12_kernel(const u16* __restrict__ in_hi, const u16* __restrict__ in_lo,
                   const u16* __restrict__ wih1, const u16* __restrict__ whh1,
                   const u16* __restrict__ wih2, const u16* __restrict__ whh2,
                   const float* __restrict__ bi1, const float* __restrict__ bh1,
                   const float* __restrict__ bi2, const float* __restrict__ bh2,
                   float* __restrict__ out_f, int N) {
    constexpr int HSTR = 76;
    const int tid = threadIdx.x;
    const int w = tid >> 6, lane = tid & 63;
    const int quad = lane >> 4, l16 = lane & 15;
    const int n0 = blockIdx.x * 16;
    const int u = w * 16 + l16;

    __shared__ __align__(16) u16 hT[2][2][16][HSTR];   // [layer][hi/lo][node][unit]
    for (int p = tid; p < 2 * 2 * 16 * HSTR; p += NTHREADS) (&hT[0][0][0][0])[p] = 0;

    short8_t fI1[4][2], fH1[4][2], fI2[4][2], fH2[4][2];
    #pragma unroll
    for (int g = 0; g < 4; ++g)
        #pragma unroll
        for (int ks = 0; ks < 2; ++ks) {
            fI1[g][ks] = *(const short8_t*)(wih1 + (long)(g * 64 + u) * 64 + ks * 32 + quad * 8);
            fH1[g][ks] = *(const short8_t*)(whh1 + (long)(g * 64 + u) * 64 + ks * 32 + quad * 8);
            fI2[g][ks] = *(const short8_t*)(wih2 + (long)(g * 64 + u) * 64 + ks * 32 + quad * 8);
            fH2[g][ks] = *(const short8_t*)(whh2 + (long)(g * 64 + u) * 64 + ks * 32 + quad * 8);
        }
    float b1[4], b2[4];
    #pragma unroll
    for (int g = 0; g < 4; ++g) {
        b1[g] = bi1[g * 64 + u] + bh1[g * 64 + u];
        b2[g] = bi2[g * 64 + u] + bh2[g * 64 + u];
    }
    float c1[4] = {}, c2[4] = {};
    __syncthreads();

    #pragma unroll 1
    for (int t = 0; t < T_STEPS; ++t) {
        // S0: read all (t-1) recurrent frags + layer-1 global input
        short8_t ainh[2], ainl[2], r1h[2], r1l[2], r2h[2], r2l[2];
        const long ibase = ((long)t * N + n0 + l16) * 64 + quad * 8;
        #pragma unroll
        for (int ks = 0; ks < 2; ++ks) {
            ainh[ks] = *(const short8_t*)(in_hi + ibase + ks * 32);
            ainl[ks] = *(const short8_t*)(in_lo + ibase + ks * 32);
            r1h[ks] = *(const short8_t*)(&hT[0][0][l16][ks * 32 + quad * 8]);
            r1l[ks] = *(const short8_t*)(&hT[0][1][l16][ks * 32 + quad * 8]);
            r2h[ks] = *(const short8_t*)(&hT[1][0][l16][ks * 32 + quad * 8]);
            r2l[ks] = *(const short8_t*)(&hT[1][1][l16][ks * 32 + quad * 8]);
        }
        __syncthreads();               // (t-1) reads done before overwrite

        // ---- layer 1 ----
        float4_t acc[4];
        #pragma unroll
        for (int g = 0; g < 4; ++g) acc[g] = (float4_t){b1[g], b1[g], b1[g], b1[g]};
        #pragma unroll
        for (int ks = 0; ks < 2; ++ks)
            #pragma unroll
            for (int g = 0; g < 4; ++g) {
                acc[g] = __builtin_amdgcn_mfma_f32_16x16x32_bf16(ainh[ks], fI1[g][ks], acc[g], 0, 0, 0);
                acc[g] = __builtin_amdgcn_mfma_f32_16x16x32_bf16(ainl[ks], fI1[g][ks], acc[g], 0, 0, 0);
                acc[g] = __builtin_amdgcn_mfma_f32_16x16x32_bf16(r1h[ks], fH1[g][ks], acc[g], 0, 0, 0);
                acc[g] = __builtin_amdgcn_mfma_f32_16x16x32_bf16(r1l[ks], fH1[g][ks], acc[g], 0, 0, 0);
            }
        #pragma unroll
        for (int r = 0; r < 4; ++r) {
            const float si = fsig(acc[0][r]);
            const float sf = fsig(acc[1][r]);
            const float gg = ftanh(acc[2][r]);
            const float so = fsig(acc[3][r]);
            const float c = sf * c1[r] + si * gg;
            c1[r] = c;
            const float h = so * ftanh(c);
            const int node = quad * 4 + r;
            const u16 hi = f2bf(h);
            hT[0][0][node][u] = hi;
            hT[0][1][node][u] = f2bf(h - bf2f(hi));
        }
        __syncthreads();               // h1(t) visible

        // ---- layer 2 (input = h1(t) from LDS) ----
        short8_t i2h[2], i2l[2];
        #pragma unroll
        for (int ks = 0; ks < 2; ++ks) {
            i2h[ks] = *(const short8_t*)(&hT[0][0][l16][ks * 32 + quad * 8]);
            i2l[ks] = *(const short8_t*)(&hT[0][1][l16][ks * 32 + quad * 8]);
        }
        #pragma unroll
        for (int g = 0; g < 4; ++g) acc[g] = (float4_t){b2[g], b2[g], b2[g], b2[g]};
        #pragma unroll
        for (int ks = 0; ks < 2; ++ks)
            #pragma unroll
            for (int g = 0; g < 4; ++g) {
                acc[g] = __builtin_amdgcn_mfma_f32_16x16x32_bf16(i2h[ks], fI2[g][ks], acc[g], 0, 0, 0);
                acc[g] = __builtin_amdgcn_mfma_f32_16x16x32_bf16(i2l[ks], fI2[g][ks], acc[g], 0, 0, 0);
                acc[g] = __builtin_amdgcn_mfma_f32_16x16x32_bf16(r2h[ks], fH2[g][ks], acc[g], 0, 0, 0);
                acc[g] = __builtin_amdgcn_mfma_f32_16x16x32_bf16(r2l[ks], fH2[g][ks], acc[g], 0, 0, 0);
            }
        #pragma unroll
        for (int r = 0; r < 4; ++r) {
            const float si = fsig(acc[0][r]);
            const float sf = fsig(acc[1][r]);
            const float gg = ftanh(acc[2][r]);
            const float so = fsig(acc[3][r]);
            const float c = sf * c2[r] + si * gg;
            c2[r] = c;
            const float h = so * ftanh(c);
            const int node = quad * 4 + r;
            if (t == T_STEPS - 1) {
                out_f[(long)(n0 + node) * 64 + u] = h;
            } else {
                const u16 hi = f2bf(h);
                hT[1][0][node][u] = hi;
                hT[1][1][node][u] = f2bf(h - bf2f(hi));
            }
        }
        __syncthreads();               // h2(t) visible for next-t S0 reads
    }
}

// ============================ launch ============================
extern "C" void kernel_launch(void* const* d_in, const int* in_sizes, int n_in,
                              void* d_out, int out_size, void* d_ws, size_t ws_size,
                              hipStream_t stream) {
    (void)n_in; (void)out_size; (void)ws_size;
    const float* x      = (const float*)d_in[0];
    const int*   ei     = (const int*)d_in[1];
    const float* w_gcn0 = (const float*)d_in[2];
    const float* b_gcn0 = (const float*)d_in[3];
    const float* w_gcn1 = (const float*)d_in[4];
    const float* b_gcn1 = (const float*)d_in[5];
    const float* w_gcn2 = (const float*)d_in[6];
    const float* b_gcn2 = (const float*)d_in[7];
    const float* bn_g0  = (const float*)d_in[8];
    const float* bn_b0  = (const float*)d_in[9];
    const float* bn_m0  = (const float*)d_in[10];
    const float* bn_v0  = (const float*)d_in[11];
    const float* bn_g1  = (const float*)d_in[12];
    const float* bn_b1  = (const float*)d_in[13];
    const float* bn_m1  = (const float*)d_in[14];
    const float* bn_v1  = (const float*)d_in[15];
    const float* w_ih_0 = (const float*)d_in[16];
    const float* w_hh_0 = (const float*)d_in[17];
    const float* b_ih_0 = (const float*)d_in[18];
    const float* b_hh_0 = (const float*)d_in[19];
    const float* w_ih_1 = (const float*)d_in[20];
    const float* w_hh_1 = (const float*)d_in[21];
    const float* b_ih_1 = (const float*)d_in[22];
    const float* b_hh_1 = (const float*)d_in[23];
    const float* w_ih_2 = (const float*)d_in[24];
    const float* w_hh_2 = (const float*)d_in[25];
    const float* b_ih_2 = (const float*)d_in[26];
    const float* b_hh_2 = (const float*)d_in[27];

    const int E = in_sizes[1] / 2;
    const int N = in_sizes[0] / (T_STEPS * F_INC);     // 10000
    const long M = (long)N * T_STEPS;                  // 80000

    char* ws = (char*)d_ws;
    size_t off = 0;
    auto carve = [&](size_t bytes) -> void* {
        void* p = ws + off;
        off += (bytes + 255) & ~(size_t)255;
        return p;
    };
    float* dis     = (float*)carve((size_t)N * 4);
    float* selfw   = (float*)carve((size_t)N * 4);
    int*   cnt     = (int*)carve((size_t)N * 4);
    int*   rowptr  = (int*)carve((size_t)(N + 1) * 4);
    int*   wp      = (int*)carve((size_t)N * 4);
    int2*  epk     = (int2*)carve((size_t)E * 8);
    int*   bsum    = (int*)carve(64 * 4);
    u16*   xb      = (u16*)carve((size_t)M * F_INC * 2);      // 5.1 MB bf16 x
    u16*   hbuf    = (u16*)carve((size_t)M * H_DIM * 2);      // 20.5 MB, [t][n][128]
    u16*   hbuf2   = (u16*)carve((size_t)M * H_DIM * 2);      // 20.5 MB ping-pong
    u16*   pA_hi   = (u16*)carve((size_t)M * O_DIM * 2);
    u16*   pA_lo   = (u16*)carve((size_t)M * O_DIM * 2);
    u16*   wt0     = (u16*)carve((size_t)128 * 32 * 2);
    u16*   wt1     = (u16*)carve((size_t)128 * 128 * 2);
    u16*   wt2     = (u16*)carve((size_t)128 * 128 * 2);
    u16*   wtih0   = (u16*)carve((size_t)256 * 128 * 2);
    u16*   wtih1   = (u16*)carve((size_t)256 * 64 * 2);
    u16*   wtih2   = (u16*)carve((size_t)256 * 64 * 2);
    u16*   whh0b   = (u16*)carve((size_t)256 * 64 * 2);
    u16*   whh1b   = (u16*)carve((size_t)256 * 64 * 2);
    u16*   whh2b   = (u16*)carve((size_t)256 * 64 * 2);

    const dim3 b256(NTHREADS);
    const int gN = (N + NTHREADS - 1) / NTHREADS;      // 40
    const int gE = (E + NTHREADS - 1) / NTHREADS;      // 782
    const int NX = (int)(M * F_INC);                   // 2.56M elements
    const int gX = (NX / 4 + NTHREADS - 1) / NTHREADS; // x-cast blocks (vec4)

    // ---- CSR count + weight prep + x->bf16 (one launch) ----
    hipMemsetAsync(cnt, 0, (size_t)N * 4, stream);
    count_wprep_kernel<<<gE + 592 + gX, b256, 0, stream>>>(
        ei, cnt, E, gE, NX, x, xb,
        w_gcn0, w_gcn1, w_gcn2, w_ih_0, w_ih_1, w_ih_2, w_hh_0, w_hh_1, w_hh_2,
        wt0, wt1, wt2, wtih0, wtih1, wtih2, whh0b, whh1b, whh2b);
    scan_part1<<<gN, b256, 0, stream>>>(cnt, bsum, N);
    scan_part3<<<gN, b256, 0, stream>>>(cnt, bsum, rowptr, wp, dis, selfw, N);
    fill_kernel<<<gE, b256, 0, stream>>>(ei, dis, wp, epk, E);

    // ---- GCN: fused agg+GEMM per layer ----
    gcn32_kernel<<<dim3(T_STEPS / 2, N / 16), b256, 0, stream>>>(
        xb, rowptr, epk, selfw, wt0, b_gcn0,
        bn_g0, bn_b0, bn_m0, bn_v0, hbuf, N);
    const dim3 gG(T_STEPS, N / 16);                     // (8, 625) single-t, XCD-pinned
    gcn128_kernel<2><<<gG, b256, 0, stream>>>(
        hbuf, rowptr, epk, selfw, wt1, b_gcn1,
        bn_g1, bn_b1, bn_m1, bn_v1, hbuf2, N);
    gcn128_kernel<1><<<gG, b256, 0, stream>>>(
        hbuf2, rowptr, epk, selfw, wt2, b_gcn2,
        nullptr, nullptr, nullptr, nullptr, hbuf, N);

    // ---- LSTM: layer0 + fused layers 1+2 ----
    const int gL = N / 16;             // 625
    lstm0_kernel<<<gL, b256, 0, stream>>>(
        hbuf, wtih0, whh0b, b_ih_0, b_hh_0, pA_hi, pA_lo, N);
    lstm12_kernel<<<gL, b256, 0, stream>>>(
        pA_hi, pA_lo, wtih1, whh1b, wtih2, whh2b,
        b_ih_1, b_hh_1, b_ih_2, b_hh_2, (float*)d_out, N);
}